// Round 5
// baseline (510.045 us; speedup 1.0000x reference)
//
#include <hip/hip_runtime.h>
#include <stdint.h>

typedef unsigned short u16;
typedef unsigned int u32;
typedef _Float16 half8 __attribute__((ext_vector_type(8)));
typedef float floatx4 __attribute__((ext_vector_type(4)));

__device__ __forceinline__ void splitf(float a, u16* hi, u16* lo) {
  union { _Float16 h; u16 u; } ch, cl;
  ch.h = (_Float16)a;
  cl.h = (_Float16)(a - (float)ch.h);
  *hi = ch.u; *lo = cl.u;
}

// ---------------- prep_w: transpose Wq/Wo into split fp16 planes [n][k] ------
__global__ void prep_w(const float* __restrict__ wq, const float* __restrict__ wo,
                       u16* __restrict__ wqt_hi, u16* __restrict__ wqt_lo,
                       u16* __restrict__ wot_hi, u16* __restrict__ wot_lo) {
  __shared__ float tile[16][17];
  const float* src = blockIdx.z ? wo : wq;
  u16* dhi = blockIdx.z ? wot_hi : wqt_hi;
  u16* dlo = blockIdx.z ? wot_lo : wqt_lo;
  int r0 = blockIdx.y * 16, c0 = blockIdx.x * 16;
  int t = threadIdx.x;
  int r = t >> 4, c = t & 15;
  tile[r][c] = src[(r0 + r) * 256 + c0 + c];
  __syncthreads();
  float a = tile[c][r];  // = src[(r0+c)][c0+r]
  int o = (c0 + r) * 256 + r0 + c;
  splitf(a, &dhi[o], &dlo[o]);
}

// ---------------- GroupNorm partial sums (fp32 x) ----------------
__global__ void gn_partial(const float* __restrict__ x, float* __restrict__ gsum,
                           float* __restrict__ gsq) {
  int blk = blockIdx.x;
  int bg = blk >> 5;        // 0..15 = b*8+g
  int chunk = blk & 31;
  int t = threadIdx.x;
  size_t base = ((size_t)bg << 20) + ((size_t)chunk << 15);
  float s = 0.f, sq = 0.f;
  for (int it = 0; it < 32; ++it) {
    float4 v = *(const float4*)(x + base + (size_t)it * 1024 + t * 4);
    s += v.x + v.y + v.z + v.w;
    sq += v.x * v.x + v.y * v.y + v.z * v.z + v.w * v.w;
  }
  for (int d = 32; d; d >>= 1) { s += __shfl_xor(s, d, 64); sq += __shfl_xor(sq, d, 64); }
  __shared__ float red[8];
  int wv = t >> 6, lane = t & 63;
  if (lane == 0) { red[wv] = s; red[4 + wv] = sq; }
  __syncthreads();
  if (t == 0) {
    atomicAdd(&gsum[bg], red[0] + red[1] + red[2] + red[3]);
    atomicAdd(&gsq[bg], red[4] + red[5] + red[6] + red[7]);
  }
}

__global__ void gn_finalize(const float* __restrict__ gsum, const float* __restrict__ gsq,
                            float* __restrict__ gmean, float* __restrict__ grstd) {
  int i = threadIdx.x;
  if (i < 16) {
    const float invN = 1.0f / 1048576.0f;
    float m = gsum[i] * invN;
    float v = gsq[i] * invN - m * m;
    gmean[i] = m;
    grstd[i] = rsqrtf(v + 1e-5f);
  }
}

// ---------------- LayerNorm(context) + K/V projections (fp32, split out) -----
__global__ void ln_kv(const float* __restrict__ ctx, const float* __restrict__ lng,
                      const float* __restrict__ lnb, const float* __restrict__ Wk,
                      const float* __restrict__ Wv,
                      u16* __restrict__ kh, u16* __restrict__ kl,
                      u16* __restrict__ vh, u16* __restrict__ vl) {
  int key = blockIdx.x;
  int b = blockIdx.y;
  int t = threadIdx.x;
  size_t ko = (size_t)(b * 96 + key) * 256 + t;
  size_t vo = ((size_t)(b * 8 + (t >> 5)) * 32 + (t & 31)) * 96 + key;
  if (key >= 77) {
    kh[ko] = 0; kl[ko] = 0; vh[vo] = 0; vl[vo] = 0;
    return;
  }
  __shared__ float lnv[768];
  __shared__ float red[8];
  const float* row = ctx + (size_t)(b * 77 + key) * 768;
  float v0 = row[t], v1 = row[t + 256], v2 = row[t + 512];
  float s = v0 + v1 + v2, sq = v0 * v0 + v1 * v1 + v2 * v2;
  for (int d = 32; d; d >>= 1) { s += __shfl_xor(s, d, 64); sq += __shfl_xor(sq, d, 64); }
  int wv = t >> 6, lane = t & 63;
  if (!lane) { red[wv] = s; red[4 + wv] = sq; }
  __syncthreads();
  float S = red[0] + red[1] + red[2] + red[3];
  float SQ = red[4] + red[5] + red[6] + red[7];
  const float invD = 1.0f / 768.0f;
  float mean = S * invD;
  float rstd = rsqrtf(SQ * invD - mean * mean + 1e-5f);
  lnv[t]       = (v0 - mean) * rstd * lng[t]       + lnb[t];
  lnv[t + 256] = (v1 - mean) * rstd * lng[t + 256] + lnb[t + 256];
  lnv[t + 512] = (v2 - mean) * rstd * lng[t + 512] + lnb[t + 512];
  __syncthreads();
  float a0 = 0.f, a1 = 0.f, a2 = 0.f, a3 = 0.f;
  float c0 = 0.f, c1 = 0.f, c2 = 0.f, c3 = 0.f;
  for (int e = 0; e < 768; e += 4) {
    float w0 = lnv[e], w1 = lnv[e + 1], w2 = lnv[e + 2], w3 = lnv[e + 3];
    a0 += w0 * Wk[(e) * 256 + t];     a1 += w1 * Wk[(e + 1) * 256 + t];
    a2 += w2 * Wk[(e + 2) * 256 + t]; a3 += w3 * Wk[(e + 3) * 256 + t];
    c0 += w0 * Wv[(e) * 256 + t];     c1 += w1 * Wv[(e + 1) * 256 + t];
    c2 += w2 * Wv[(e + 2) * 256 + t]; c3 += w3 * Wv[(e + 3) * 256 + t];
  }
  float ak = (a0 + a1) + (a2 + a3);
  float av = (c0 + c1) + (c2 + c3);
  splitf(ak, &kh[ko], &kl[ko]);
  splitf(av, &vh[vo], &vl[vo]);
}

// ---------------- fused Q-proj + attention + out-proj (fp16x2 split MFMA) ----
// grid 2048: b = blk>>10, s0 = (blk&1023)*32. 256 threads = 4 waves.
// Static LDS 64 KB: qs pairs (32 KB, also A-stage) + B-stage pairs (32 KB, also P).
__global__ __launch_bounds__(256) void fused_qao(
    const float* __restrict__ x,
    const u16* __restrict__ wqt_hi, const u16* __restrict__ wqt_lo,
    const u16* __restrict__ wot_hi, const u16* __restrict__ wot_lo,
    const u16* __restrict__ kws_hi, const u16* __restrict__ kws_lo,
    const u16* __restrict__ vtw_hi, const u16* __restrict__ vtw_lo,
    const float* __restrict__ gng, const float* __restrict__ gnb,
    const float* __restrict__ gmean, const float* __restrict__ grstd,
    const float* __restrict__ bo, float* __restrict__ out) {
  __shared__ u16 qhi[32 * 256];   // Q/attn_out hi plane; first 1 KB doubles as A-stage hi
  __shared__ u16 qlo[32 * 256];
  __shared__ u16 bsh[256 * 32];   // B-stage hi plane; doubles as P-stage hi [4][16][112]
  __shared__ u16 bsl[256 * 32];
  int t = threadIdx.x, lane = t & 63, wv = t >> 6;
  int ml = lane & 15, quad = lane >> 4;
  int b = blockIdx.x >> 10;
  int s0 = (blockIdx.x & 1023) * 32;

  int ci = t >> 3, sl4 = (t & 7) * 4;   // A staging: channel-local, s-local
  int rowB = t >> 2, ch = (t & 3) * 8;  // B staging: n-local, k-local

  floatx4 acc[2][4];
#pragma unroll
  for (int i = 0; i < 2; ++i)
#pragma unroll
    for (int j = 0; j < 4; ++j) acc[i][j] = (floatx4){0.f, 0.f, 0.f, 0.f};

  // ---- Step A: Q[32][256] = GN(x)^T @ Wq ----
  for (int k0 = 0; k0 < 256; k0 += 32) {
    int c = k0 + ci;
    int bg = b * 8 + (c >> 5);
    float mean = gmean[bg], rstd = grstd[bg];
    float scale = rstd * gng[c];
    float shift = gnb[c] - mean * scale;
    float4 xv = *(const float4*)(x + (((size_t)(b * 256 + c)) << 15) + s0 + sl4);
    uint4 wh[4], wl[4];
#pragma unroll
    for (int j = 0; j < 4; ++j) {
      size_t wo_ = (size_t)(rowB + 64 * j) * 256 + k0 + ch;
      wh[j] = *(const uint4*)(wqt_hi + wo_);
      wl[j] = *(const uint4*)(wqt_lo + wo_);
    }
    __syncthreads();
    float xa[4] = {xv.x, xv.y, xv.z, xv.w};
#pragma unroll
    for (int e = 0; e < 4; ++e) {
      int o = (sl4 + e) * 32 + ci;
      splitf(xa[e] * scale + shift, &qhi[o], &qlo[o]);
    }
#pragma unroll
    for (int j = 0; j < 4; ++j) {
      *(uint4*)&bsh[(rowB + 64 * j) * 32 + ch] = wh[j];
      *(uint4*)&bsl[(rowB + 64 * j) * 32 + ch] = wl[j];
    }
    __syncthreads();
    half8 ah[2], al[2], bh[4], bl[4];
#pragma unroll
    for (int i = 0; i < 2; ++i) {
      ah[i] = *(const half8*)&qhi[(i * 16 + ml) * 32 + quad * 8];
      al[i] = *(const half8*)&qlo[(i * 16 + ml) * 32 + quad * 8];
    }
#pragma unroll
    for (int j = 0; j < 4; ++j) {
      bh[j] = *(const half8*)&bsh[(wv * 64 + j * 16 + ml) * 32 + quad * 8];
      bl[j] = *(const half8*)&bsl[(wv * 64 + j * 16 + ml) * 32 + quad * 8];
    }
#pragma unroll
    for (int i = 0; i < 2; ++i)
#pragma unroll
      for (int j = 0; j < 4; ++j) {
        acc[i][j] = __builtin_amdgcn_mfma_f32_16x16x32_f16(al[i], bh[j], acc[i][j], 0, 0, 0);
        acc[i][j] = __builtin_amdgcn_mfma_f32_16x16x32_f16(ah[i], bl[j], acc[i][j], 0, 0, 0);
        acc[i][j] = __builtin_amdgcn_mfma_f32_16x16x32_f16(ah[i], bh[j], acc[i][j], 0, 0, 0);
      }
  }
  __syncthreads();  // all waves done reading A-stage region of qhi/qlo
#pragma unroll
  for (int i = 0; i < 2; ++i)
#pragma unroll
    for (int j = 0; j < 4; ++j)
#pragma unroll
      for (int r = 0; r < 4; ++r) {
        int o = (i * 16 + quad * 4 + r) * 256 + wv * 64 + j * 16 + ml;
        splitf(acc[i][j][r], &qhi[o], &qlo[o]);
      }
  // zero P pad cols 80..95 (own wave slab)
  u16* ph = bsh;  // [wv][16][112]
  u16* pl = bsl;
#pragma unroll
  for (int jj = 0; jj < 4; ++jj) {
    int o = wv * 1792 + ml * 112 + 80 + quad * 4 + jj;
    ph[o] = 0; pl[o] = 0;
  }
  __syncthreads();  // qs complete (cross-wave columns)

  // ---- Step B: attention. wave -> rows (wv&1)*16.., heads (wv>>1)*4.. ----
  int r16 = (wv & 1) * 16;
  const float scl = 0.17677669529663687f;
  const floatx4 z = {0.f, 0.f, 0.f, 0.f};
  for (int hh = 0; hh < 4; ++hh) {
    int h = (wv >> 1) * 4 + hh;
    half8 qfh = *(const half8*)&qhi[(r16 + ml) * 256 + h * 32 + quad * 8];
    half8 qfl = *(const half8*)&qlo[(r16 + ml) * 256 + h * 32 + quad * 8];
    floatx4 sc[5];
#pragma unroll
    for (int kt = 0; kt < 5; ++kt) {
      size_t ko = (size_t)(b * 96 + kt * 16 + ml) * 256 + h * 32 + quad * 8;
      half8 kfh = *(const half8*)(kws_hi + ko);
      half8 kfl = *(const half8*)(kws_lo + ko);
      floatx4 a = __builtin_amdgcn_mfma_f32_16x16x32_f16(qfl, kfh, z, 0, 0, 0);
      a = __builtin_amdgcn_mfma_f32_16x16x32_f16(qfh, kfl, a, 0, 0, 0);
      sc[kt] = __builtin_amdgcn_mfma_f32_16x16x32_f16(qfh, kfh, a, 0, 0, 0);
    }
    float mx[4] = {-1e30f, -1e30f, -1e30f, -1e30f};
#pragma unroll
    for (int kt = 0; kt < 5; ++kt) {
      int col = kt * 16 + ml;
#pragma unroll
      for (int r = 0; r < 4; ++r) {
        float v = (col < 77) ? sc[kt][r] * scl : -1e30f;
        sc[kt][r] = v;
        mx[r] = fmaxf(mx[r], v);
      }
    }
#pragma unroll
    for (int d = 1; d < 16; d <<= 1)
#pragma unroll
      for (int r = 0; r < 4; ++r) mx[r] = fmaxf(mx[r], __shfl_xor(mx[r], d, 64));
    float sm[4] = {0.f, 0.f, 0.f, 0.f};
#pragma unroll
    for (int kt = 0; kt < 5; ++kt)
#pragma unroll
      for (int r = 0; r < 4; ++r) {
        float p = __expf(sc[kt][r] - mx[r]);
        sc[kt][r] = p;
        sm[r] += p;
      }
#pragma unroll
    for (int d = 1; d < 16; d <<= 1)
#pragma unroll
      for (int r = 0; r < 4; ++r) sm[r] += __shfl_xor(sm[r], d, 64);
    float inv[4];
#pragma unroll
    for (int r = 0; r < 4; ++r) inv[r] = 1.0f / sm[r];
#pragma unroll
    for (int kt = 0; kt < 5; ++kt) {
      int col = kt * 16 + ml;
#pragma unroll
      for (int r = 0; r < 4; ++r) {
        int o = wv * 1792 + (quad * 4 + r) * 112 + col;
        splitf(sc[kt][r] * inv[r], &ph[o], &pl[o]);
      }
    }
    __syncthreads();
    floatx4 o0 = z, o1 = z;
#pragma unroll
    for (int ks = 0; ks < 3; ++ks) {
      half8 pfh = *(const half8*)&ph[wv * 1792 + ml * 112 + ks * 32 + quad * 8];
      half8 pfl = *(const half8*)&pl[wv * 1792 + ml * 112 + ks * 32 + quad * 8];
      size_t v0o = (size_t)((b * 8 + h) * 32 + ml) * 96 + ks * 32 + quad * 8;
      size_t v1o = (size_t)((b * 8 + h) * 32 + 16 + ml) * 96 + ks * 32 + quad * 8;
      half8 v0h = *(const half8*)(vtw_hi + v0o);
      half8 v0l = *(const half8*)(vtw_lo + v0o);
      half8 v1h = *(const half8*)(vtw_hi + v1o);
      half8 v1l = *(const half8*)(vtw_lo + v1o);
      o0 = __builtin_amdgcn_mfma_f32_16x16x32_f16(pfl, v0h, o0, 0, 0, 0);
      o0 = __builtin_amdgcn_mfma_f32_16x16x32_f16(pfh, v0l, o0, 0, 0, 0);
      o0 = __builtin_amdgcn_mfma_f32_16x16x32_f16(pfh, v0h, o0, 0, 0, 0);
      o1 = __builtin_amdgcn_mfma_f32_16x16x32_f16(pfl, v1h, o1, 0, 0, 0);
      o1 = __builtin_amdgcn_mfma_f32_16x16x32_f16(pfh, v1l, o1, 0, 0, 0);
      o1 = __builtin_amdgcn_mfma_f32_16x16x32_f16(pfh, v1h, o1, 0, 0, 0);
    }
#pragma unroll
    for (int r = 0; r < 4; ++r) {
      int o = (r16 + quad * 4 + r) * 256 + h * 32;
      splitf(o0[r], &qhi[o + ml], &qlo[o + ml]);
      splitf(o1[r], &qhi[o + 16 + ml], &qlo[o + 16 + ml]);
    }
    __syncthreads();
  }

  // ---- Step C: out[32][256] = attn_out @ Wo; transposed residual store ----
#pragma unroll
  for (int i = 0; i < 2; ++i)
#pragma unroll
    for (int j = 0; j < 4; ++j) acc[i][j] = (floatx4){0.f, 0.f, 0.f, 0.f};
  for (int k0 = 0; k0 < 256; k0 += 32) {
    uint4 wh[4], wl[4];
#pragma unroll
    for (int j = 0; j < 4; ++j) {
      size_t wo_ = (size_t)(rowB + 64 * j) * 256 + k0 + ch;
      wh[j] = *(const uint4*)(wot_hi + wo_);
      wl[j] = *(const uint4*)(wot_lo + wo_);
    }
    __syncthreads();
#pragma unroll
    for (int j = 0; j < 4; ++j) {
      *(uint4*)&bsh[(rowB + 64 * j) * 32 + ch] = wh[j];
      *(uint4*)&bsl[(rowB + 64 * j) * 32 + ch] = wl[j];
    }
    __syncthreads();
    half8 ah[2], al[2], bh[4], bl[4];
#pragma unroll
    for (int i = 0; i < 2; ++i) {
      ah[i] = *(const half8*)&qhi[(i * 16 + ml) * 256 + k0 + quad * 8];
      al[i] = *(const half8*)&qlo[(i * 16 + ml) * 256 + k0 + quad * 8];
    }
#pragma unroll
    for (int j = 0; j < 4; ++j) {
      bh[j] = *(const half8*)&bsh[(wv * 64 + j * 16 + ml) * 32 + quad * 8];
      bl[j] = *(const half8*)&bsl[(wv * 64 + j * 16 + ml) * 32 + quad * 8];
    }
#pragma unroll
    for (int i = 0; i < 2; ++i)
#pragma unroll
      for (int j = 0; j < 4; ++j) {
        acc[i][j] = __builtin_amdgcn_mfma_f32_16x16x32_f16(al[i], bh[j], acc[i][j], 0, 0, 0);
        acc[i][j] = __builtin_amdgcn_mfma_f32_16x16x32_f16(ah[i], bl[j], acc[i][j], 0, 0, 0);
        acc[i][j] = __builtin_amdgcn_mfma_f32_16x16x32_f16(ah[i], bh[j], acc[i][j], 0, 0, 0);
      }
  }
#pragma unroll
  for (int i = 0; i < 2; ++i) {
    int sp = s0 + i * 16 + quad * 4;
#pragma unroll
    for (int j = 0; j < 4; ++j) {
      int col = wv * 64 + j * 16 + ml;
      float bias = bo[col];
      size_t o = (((size_t)(b * 256 + col)) << 15) + sp;
      float4 xv = *(const float4*)(x + o);
      float4 ov;
      ov.x = acc[i][j][0] + bias + xv.x;
      ov.y = acc[i][j][1] + bias + xv.y;
      ov.z = acc[i][j][2] + bias + xv.z;
      ov.w = acc[i][j][3] + bias + xv.w;
      *(float4*)(out + o) = ov;
    }
  }
}

extern "C" void kernel_launch(void* const* d_in, const int* in_sizes, int n_in,
                              void* d_out, int out_size, void* d_ws, size_t ws_size,
                              hipStream_t stream) {
  (void)out_size; (void)ws_size;
  // Input remap: dict order default; alphabetical fallback (disambiguated by sizes).
  int idx[11] = {0, 1, 2, 3, 4, 5, 6, 7, 8, 9, 10};  // x,ctx,gng,gnb,lng,lnb,Wq,Wk,Wv,Wo,bo
  static const int dsz[11] = {16777216, 118272, 256, 256, 768, 768,
                              65536, 196608, 196608, 65536, 256};
  bool dict = (n_in == 11);
  if (dict)
    for (int i = 0; i < 11; ++i)
      if (in_sizes[i] != dsz[i]) { dict = false; break; }
  if (!dict && n_in == 11) {
    static const int ssz[11] = {196608, 65536, 65536, 196608, 256, 118272,
                                256, 256, 768, 768, 16777216};
    bool srt = true;
    for (int i = 0; i < 11; ++i)
      if (in_sizes[i] != ssz[i]) { srt = false; break; }
    if (srt) {
      idx[0] = 10; idx[1] = 5; idx[2] = 7; idx[3] = 6; idx[4] = 9; idx[5] = 8;
      idx[6] = 2;  idx[7] = 0; idx[8] = 3; idx[9] = 1; idx[10] = 4;
    }
  }
  const float* x   = (const float*)d_in[idx[0]];
  const float* ctx = (const float*)d_in[idx[1]];
  const float* gng = (const float*)d_in[idx[2]];
  const float* gnb = (const float*)d_in[idx[3]];
  const float* lng = (const float*)d_in[idx[4]];
  const float* lnb = (const float*)d_in[idx[5]];
  const float* Wq  = (const float*)d_in[idx[6]];
  const float* Wk  = (const float*)d_in[idx[7]];
  const float* Wv  = (const float*)d_in[idx[8]];
  const float* Wo  = (const float*)d_in[idx[9]];
  const float* bo  = (const float*)d_in[idx[10]];
  float* out = (float*)d_out;

  // d_ws layout (u16 units): stats 128 | wqt_hi 64K | wqt_lo | wot_hi | wot_lo
  //                          | kws_hi 48K | kws_lo | vtw_hi | vtw_lo  (~918 KB)
  u16* ws = (u16*)d_ws;
  float* stats = (float*)ws;
  float* gsum = stats, *gsq = stats + 16, *gmean = stats + 32, *grstd = stats + 48;
  u16* wqt_hi = ws + 128;
  u16* wqt_lo = wqt_hi + 65536;
  u16* wot_hi = wqt_lo + 65536;
  u16* wot_lo = wot_hi + 65536;
  u16* kws_hi = wot_lo + 65536;
  u16* kws_lo = kws_hi + 49152;
  u16* vtw_hi = kws_lo + 49152;
  u16* vtw_lo = vtw_hi + 49152;

  hipMemsetAsync(gsum, 0, 32 * sizeof(float), stream);
  prep_w<<<dim3(16, 16, 2), 256, 0, stream>>>(Wq, Wo, wqt_hi, wqt_lo, wot_hi, wot_lo);
  gn_partial<<<512, 256, 0, stream>>>(x, gsum, gsq);
  gn_finalize<<<1, 64, 0, stream>>>(gsum, gsq, gmean, grstd);
  ln_kv<<<dim3(96, 2), 256, 0, stream>>>(ctx, lng, lnb, Wk, Wv,
                                         kws_hi, kws_lo, vtw_hi, vtw_lo);
  fused_qao<<<2048, 256, 0, stream>>>(x, wqt_hi, wqt_lo, wot_hi, wot_lo,
                                      kws_hi, kws_lo, vtw_hi, vtw_lo,
                                      gng, gnb, gmean, grstd, bo, out);
}

// Round 6
// 368.024 us; speedup vs baseline: 1.3859x; 1.3859x over previous
//
#include <hip/hip_runtime.h>
#include <stdint.h>

typedef unsigned short u16;
typedef unsigned int u32;
typedef _Float16 half8 __attribute__((ext_vector_type(8)));
typedef float floatx4 __attribute__((ext_vector_type(4)));

__device__ __forceinline__ void splitf(float a, u16* hi, u16* lo) {
  union { _Float16 h; u16 u; } ch, cl;
  ch.h = (_Float16)a;
  cl.h = (_Float16)(a - (float)ch.h);
  *hi = ch.u; *lo = cl.u;
}

// ---------------- prep_w: transpose Wq/Wo into split fp16 planes [n][k] ------
// Also zeroes the GN stats accumulators (block 0).
__global__ void prep_w(const float* __restrict__ wq, const float* __restrict__ wo,
                       u16* __restrict__ wqt_hi, u16* __restrict__ wqt_lo,
                       u16* __restrict__ wot_hi, u16* __restrict__ wot_lo,
                       float* __restrict__ stats) {
  __shared__ float tile[16][17];
  int t = threadIdx.x;
  if (blockIdx.x == 0 && blockIdx.y == 0 && blockIdx.z == 0 && t < 32) stats[t] = 0.f;
  const float* src = blockIdx.z ? wo : wq;
  u16* dhi = blockIdx.z ? wot_hi : wqt_hi;
  u16* dlo = blockIdx.z ? wot_lo : wqt_lo;
  int r0 = blockIdx.y * 16, c0 = blockIdx.x * 16;
  int r = t >> 4, c = t & 15;
  tile[r][c] = src[(r0 + r) * 256 + c0 + c];
  __syncthreads();
  float a = tile[c][r];
  int o = (c0 + r) * 256 + r0 + c;
  splitf(a, &dhi[o], &dlo[o]);
}

// ---------------- GroupNorm partial sums ----------------
__global__ void gn_partial(const float* __restrict__ x, float* __restrict__ gsum,
                           float* __restrict__ gsq) {
  int blk = blockIdx.x;
  int bg = blk >> 5;
  int chunk = blk & 31;
  int t = threadIdx.x;
  size_t base = ((size_t)bg << 20) + ((size_t)chunk << 15);
  float s = 0.f, sq = 0.f;
  for (int it = 0; it < 32; ++it) {
    float4 v = *(const float4*)(x + base + (size_t)it * 1024 + t * 4);
    s += v.x + v.y + v.z + v.w;
    sq += v.x * v.x + v.y * v.y + v.z * v.z + v.w * v.w;
  }
  for (int d = 32; d; d >>= 1) { s += __shfl_xor(s, d, 64); sq += __shfl_xor(sq, d, 64); }
  __shared__ float red[8];
  int wv = t >> 6, lane = t & 63;
  if (lane == 0) { red[wv] = s; red[4 + wv] = sq; }
  __syncthreads();
  if (t == 0) {
    atomicAdd(&gsum[bg], red[0] + red[1] + red[2] + red[3]);
    atomicAdd(&gsq[bg], red[4] + red[5] + red[6] + red[7]);
  }
}

// ---------------- LayerNorm(context) + K/V projections ----------------
__global__ void ln_kv(const float* __restrict__ ctx, const float* __restrict__ lng,
                      const float* __restrict__ lnb, const float* __restrict__ Wk,
                      const float* __restrict__ Wv,
                      u16* __restrict__ kh, u16* __restrict__ kl,
                      u16* __restrict__ vh, u16* __restrict__ vl) {
  int key = blockIdx.x;
  int b = blockIdx.y;
  int t = threadIdx.x;
  size_t ko = (size_t)(b * 96 + key) * 256 + t;
  size_t vo = ((size_t)(b * 8 + (t >> 5)) * 32 + (t & 31)) * 96 + key;
  if (key >= 77) {
    kh[ko] = 0; kl[ko] = 0; vh[vo] = 0; vl[vo] = 0;
    return;
  }
  __shared__ float lnv[768];
  __shared__ float red[8];
  const float* row = ctx + (size_t)(b * 77 + key) * 768;
  float v0 = row[t], v1 = row[t + 256], v2 = row[t + 512];
  float s = v0 + v1 + v2, sq = v0 * v0 + v1 * v1 + v2 * v2;
  for (int d = 32; d; d >>= 1) { s += __shfl_xor(s, d, 64); sq += __shfl_xor(sq, d, 64); }
  int wv = t >> 6, lane = t & 63;
  if (!lane) { red[wv] = s; red[4 + wv] = sq; }
  __syncthreads();
  float S = red[0] + red[1] + red[2] + red[3];
  float SQ = red[4] + red[5] + red[6] + red[7];
  const float invD = 1.0f / 768.0f;
  float mean = S * invD;
  float rstd = rsqrtf(SQ * invD - mean * mean + 1e-5f);
  lnv[t]       = (v0 - mean) * rstd * lng[t]       + lnb[t];
  lnv[t + 256] = (v1 - mean) * rstd * lng[t + 256] + lnb[t + 256];
  lnv[t + 512] = (v2 - mean) * rstd * lng[t + 512] + lnb[t + 512];
  __syncthreads();
  float a0 = 0.f, a1 = 0.f, a2 = 0.f, a3 = 0.f;
  float c0 = 0.f, c1 = 0.f, c2 = 0.f, c3 = 0.f;
  for (int e = 0; e < 768; e += 4) {
    float w0 = lnv[e], w1 = lnv[e + 1], w2 = lnv[e + 2], w3 = lnv[e + 3];
    a0 += w0 * Wk[(e) * 256 + t];     a1 += w1 * Wk[(e + 1) * 256 + t];
    a2 += w2 * Wk[(e + 2) * 256 + t]; a3 += w3 * Wk[(e + 3) * 256 + t];
    c0 += w0 * Wv[(e) * 256 + t];     c1 += w1 * Wv[(e + 1) * 256 + t];
    c2 += w2 * Wv[(e + 2) * 256 + t]; c3 += w3 * Wv[(e + 3) * 256 + t];
  }
  float ak = (a0 + a1) + (a2 + a3);
  float av = (c0 + c1) + (c2 + c3);
  splitf(ak, &kh[ko], &kl[ko]);
  splitf(av, &vh[vo], &vl[vo]);
}

// ---------------- fused Q-proj + attention + out-proj ----------------
// grid 2048: b = blk>>10, s0 = (blk&1023)*32. 256 threads = 4 waves.
// B-fragments load DIRECTLY from global (pre-split, pre-transposed weights in
// L2) -> zero barriers inside the GEMM k-loops. A-tile staged once in qs.
#define QSTR 264   // qs row stride (u16): 16B-aligned rows, +4 bank shift/row
#define PSTR 120   // P row stride (u16)
__global__ __launch_bounds__(256, 2) void fused_qao(
    const float* __restrict__ x,
    const u16* __restrict__ wqt_hi, const u16* __restrict__ wqt_lo,
    const u16* __restrict__ wot_hi, const u16* __restrict__ wot_lo,
    const u16* __restrict__ kws_hi, const u16* __restrict__ kws_lo,
    const u16* __restrict__ vtw_hi, const u16* __restrict__ vtw_lo,
    const float* __restrict__ gng, const float* __restrict__ gnb,
    const float* __restrict__ gsum, const float* __restrict__ gsq,
    const float* __restrict__ bo, float* __restrict__ out) {
  __shared__ u16 qhi[32 * QSTR];  // GN(x)^T tile during Step A; then Q; then attn_out
  __shared__ u16 qlo[32 * QSTR];
  __shared__ u16 ph[4 * 16 * PSTR];
  __shared__ u16 pl[4 * 16 * PSTR];
  int t = threadIdx.x, lane = t & 63, wv = t >> 6;
  int ml = lane & 15, quad = lane >> 4;
  int b = blockIdx.x >> 10;
  int s0 = (blockIdx.x & 1023) * 32;

  // ---- Stage GN(x)^T tile [32 s][256 c] into qs (hi/lo), finalize GN inline.
  {
    const float invN = 1.0f / 1048576.0f;
    int sc = (t & 7) * 4;  // s-chunk start
#pragma unroll
    for (int p = 0; p < 8; ++p) {
      int c = p * 32 + (t >> 3);
      int bg = b * 8 + (c >> 5);
      float mean = gsum[bg] * invN;
      float var = gsq[bg] * invN - mean * mean;
      float rstd = rsqrtf(var + 1e-5f);
      float scale = rstd * gng[c];
      float shift = gnb[c] - mean * scale;
      float4 xv = *(const float4*)(x + (((size_t)(b * 256 + c)) << 15) + s0 + sc);
      float xa[4] = {xv.x, xv.y, xv.z, xv.w};
#pragma unroll
      for (int e = 0; e < 4; ++e) {
        int o = (sc + e) * QSTR + c;
        splitf(xa[e] * scale + shift, &qhi[o], &qlo[o]);
      }
    }
  }
  __syncthreads();

  // ---- Step A: Q[32][256] = A-tile @ Wq^T. No barriers in k-loop.
  floatx4 acc[2][4];
#pragma unroll
  for (int i = 0; i < 2; ++i)
#pragma unroll
    for (int j = 0; j < 4; ++j) acc[i][j] = (floatx4){0.f, 0.f, 0.f, 0.f};
#pragma unroll
  for (int k0 = 0; k0 < 256; k0 += 32) {
    half8 ah[2], al[2], bh[4], bl[4];
#pragma unroll
    for (int j = 0; j < 4; ++j) {
      size_t wo_ = (size_t)(wv * 64 + j * 16 + ml) * 256 + k0 + quad * 8;
      bh[j] = *(const half8*)(wqt_hi + wo_);
      bl[j] = *(const half8*)(wqt_lo + wo_);
    }
#pragma unroll
    for (int i = 0; i < 2; ++i) {
      ah[i] = *(const half8*)&qhi[(i * 16 + ml) * QSTR + k0 + quad * 8];
      al[i] = *(const half8*)&qlo[(i * 16 + ml) * QSTR + k0 + quad * 8];
    }
#pragma unroll
    for (int i = 0; i < 2; ++i)
#pragma unroll
      for (int j = 0; j < 4; ++j) {
        acc[i][j] = __builtin_amdgcn_mfma_f32_16x16x32_f16(al[i], bh[j], acc[i][j], 0, 0, 0);
        acc[i][j] = __builtin_amdgcn_mfma_f32_16x16x32_f16(ah[i], bl[j], acc[i][j], 0, 0, 0);
        acc[i][j] = __builtin_amdgcn_mfma_f32_16x16x32_f16(ah[i], bh[j], acc[i][j], 0, 0, 0);
      }
  }
  __syncthreads();  // all waves done reading A-tile before overwriting with Q
#pragma unroll
  for (int i = 0; i < 2; ++i)
#pragma unroll
    for (int j = 0; j < 4; ++j)
#pragma unroll
      for (int r = 0; r < 4; ++r) {
        int o = (i * 16 + quad * 4 + r) * QSTR + wv * 64 + j * 16 + ml;
        splitf(acc[i][j][r], &qhi[o], &qlo[o]);
      }
  // zero P pad cols 80..95 (both planes), once
#pragma unroll
  for (int jj = 0; jj < 4; ++jj) {
    int o = wv * 16 * PSTR + ml * PSTR + 80 + quad * 4 + jj;
    ph[o] = 0; pl[o] = 0;
  }
  __syncthreads();  // Q complete (cross-wave columns)

  // ---- Step B: attention. wave -> rows (wv&1)*16.., heads (wv>>1)*4..
  int r16 = (wv & 1) * 16;
  const float scl = 0.17677669529663687f;
  const floatx4 z = {0.f, 0.f, 0.f, 0.f};
  for (int hh = 0; hh < 4; ++hh) {
    int h = (wv >> 1) * 4 + hh;
    half8 qfh = *(const half8*)&qhi[(r16 + ml) * QSTR + h * 32 + quad * 8];
    half8 qfl = *(const half8*)&qlo[(r16 + ml) * QSTR + h * 32 + quad * 8];
    floatx4 sc[5];
#pragma unroll
    for (int kt = 0; kt < 5; ++kt) {
      size_t ko = (size_t)(b * 96 + kt * 16 + ml) * 256 + h * 32 + quad * 8;
      half8 kfh = *(const half8*)(kws_hi + ko);
      half8 kfl = *(const half8*)(kws_lo + ko);
      floatx4 a = __builtin_amdgcn_mfma_f32_16x16x32_f16(qfl, kfh, z, 0, 0, 0);
      a = __builtin_amdgcn_mfma_f32_16x16x32_f16(qfh, kfl, a, 0, 0, 0);
      sc[kt] = __builtin_amdgcn_mfma_f32_16x16x32_f16(qfh, kfh, a, 0, 0, 0);
    }
    float mx[4] = {-1e30f, -1e30f, -1e30f, -1e30f};
#pragma unroll
    for (int kt = 0; kt < 5; ++kt) {
      int col = kt * 16 + ml;
#pragma unroll
      for (int r = 0; r < 4; ++r) {
        float v = (col < 77) ? sc[kt][r] * scl : -1e30f;
        sc[kt][r] = v;
        mx[r] = fmaxf(mx[r], v);
      }
    }
#pragma unroll
    for (int d = 1; d < 16; d <<= 1)
#pragma unroll
      for (int r = 0; r < 4; ++r) mx[r] = fmaxf(mx[r], __shfl_xor(mx[r], d, 64));
    float sm[4] = {0.f, 0.f, 0.f, 0.f};
#pragma unroll
    for (int kt = 0; kt < 5; ++kt)
#pragma unroll
      for (int r = 0; r < 4; ++r) {
        float p = __expf(sc[kt][r] - mx[r]);
        sc[kt][r] = p;
        sm[r] += p;
      }
#pragma unroll
    for (int d = 1; d < 16; d <<= 1)
#pragma unroll
      for (int r = 0; r < 4; ++r) sm[r] += __shfl_xor(sm[r], d, 64);
    float inv[4];
#pragma unroll
    for (int r = 0; r < 4; ++r) inv[r] = 1.0f / sm[r];
#pragma unroll
    for (int kt = 0; kt < 5; ++kt) {
      int col = kt * 16 + ml;
#pragma unroll
      for (int r = 0; r < 4; ++r) {
        int o = wv * 16 * PSTR + (quad * 4 + r) * PSTR + col;
        splitf(sc[kt][r] * inv[r], &ph[o], &pl[o]);
      }
    }
    __syncthreads();  // cheap insurance for P write->read (wave-private slabs)
    floatx4 o0 = z, o1 = z;
#pragma unroll
    for (int ks = 0; ks < 3; ++ks) {
      half8 pfh = *(const half8*)&ph[wv * 16 * PSTR + ml * PSTR + ks * 32 + quad * 8];
      half8 pfl = *(const half8*)&pl[wv * 16 * PSTR + ml * PSTR + ks * 32 + quad * 8];
      size_t v0o = (size_t)((b * 8 + h) * 32 + ml) * 96 + ks * 32 + quad * 8;
      size_t v1o = (size_t)((b * 8 + h) * 32 + 16 + ml) * 96 + ks * 32 + quad * 8;
      half8 v0h = *(const half8*)(vtw_hi + v0o);
      half8 v0l = *(const half8*)(vtw_lo + v0o);
      half8 v1h = *(const half8*)(vtw_hi + v1o);
      half8 v1l = *(const half8*)(vtw_lo + v1o);
      o0 = __builtin_amdgcn_mfma_f32_16x16x32_f16(pfl, v0h, o0, 0, 0, 0);
      o0 = __builtin_amdgcn_mfma_f32_16x16x32_f16(pfh, v0l, o0, 0, 0, 0);
      o0 = __builtin_amdgcn_mfma_f32_16x16x32_f16(pfh, v0h, o0, 0, 0, 0);
      o1 = __builtin_amdgcn_mfma_f32_16x16x32_f16(pfl, v1h, o1, 0, 0, 0);
      o1 = __builtin_amdgcn_mfma_f32_16x16x32_f16(pfh, v1l, o1, 0, 0, 0);
      o1 = __builtin_amdgcn_mfma_f32_16x16x32_f16(pfh, v1h, o1, 0, 0, 0);
    }
    // write back into qs: rows r16.., cols h*32.. — disjoint across waves
#pragma unroll
    for (int r = 0; r < 4; ++r) {
      int o = (r16 + quad * 4 + r) * QSTR + h * 32;
      splitf(o0[r], &qhi[o + ml], &qlo[o + ml]);
      splitf(o1[r], &qhi[o + 16 + ml], &qlo[o + 16 + ml]);
    }
  }
  __syncthreads();  // attn_out complete before Step C reads all columns

  // ---- Step C: out = attn_out @ Wo^T + bo + x. No barriers in k-loop.
#pragma unroll
  for (int i = 0; i < 2; ++i)
#pragma unroll
    for (int j = 0; j < 4; ++j) acc[i][j] = (floatx4){0.f, 0.f, 0.f, 0.f};
#pragma unroll
  for (int k0 = 0; k0 < 256; k0 += 32) {
    half8 ah[2], al[2], bh[4], bl[4];
#pragma unroll
    for (int j = 0; j < 4; ++j) {
      size_t wo_ = (size_t)(wv * 64 + j * 16 + ml) * 256 + k0 + quad * 8;
      bh[j] = *(const half8*)(wot_hi + wo_);
      bl[j] = *(const half8*)(wot_lo + wo_);
    }
#pragma unroll
    for (int i = 0; i < 2; ++i) {
      ah[i] = *(const half8*)&qhi[(i * 16 + ml) * QSTR + k0 + quad * 8];
      al[i] = *(const half8*)&qlo[(i * 16 + ml) * QSTR + k0 + quad * 8];
    }
#pragma unroll
    for (int i = 0; i < 2; ++i)
#pragma unroll
      for (int j = 0; j < 4; ++j) {
        acc[i][j] = __builtin_amdgcn_mfma_f32_16x16x32_f16(al[i], bh[j], acc[i][j], 0, 0, 0);
        acc[i][j] = __builtin_amdgcn_mfma_f32_16x16x32_f16(ah[i], bl[j], acc[i][j], 0, 0, 0);
        acc[i][j] = __builtin_amdgcn_mfma_f32_16x16x32_f16(ah[i], bh[j], acc[i][j], 0, 0, 0);
      }
  }
#pragma unroll
  for (int i = 0; i < 2; ++i) {
    int sp = s0 + i * 16 + quad * 4;
#pragma unroll
    for (int j = 0; j < 4; ++j) {
      int col = wv * 64 + j * 16 + ml;
      float bias = bo[col];
      size_t o = (((size_t)(b * 256 + col)) << 15) + sp;
      float4 xv = *(const float4*)(x + o);
      float4 ov;
      ov.x = acc[i][j][0] + bias + xv.x;
      ov.y = acc[i][j][1] + bias + xv.y;
      ov.z = acc[i][j][2] + bias + xv.z;
      ov.w = acc[i][j][3] + bias + xv.w;
      *(float4*)(out + o) = ov;
    }
  }
}

extern "C" void kernel_launch(void* const* d_in, const int* in_sizes, int n_in,
                              void* d_out, int out_size, void* d_ws, size_t ws_size,
                              hipStream_t stream) {
  (void)out_size; (void)ws_size;
  int idx[11] = {0, 1, 2, 3, 4, 5, 6, 7, 8, 9, 10};  // x,ctx,gng,gnb,lng,lnb,Wq,Wk,Wv,Wo,bo
  static const int dsz[11] = {16777216, 118272, 256, 256, 768, 768,
                              65536, 196608, 196608, 65536, 256};
  bool dict = (n_in == 11);
  if (dict)
    for (int i = 0; i < 11; ++i)
      if (in_sizes[i] != dsz[i]) { dict = false; break; }
  if (!dict && n_in == 11) {
    static const int ssz[11] = {196608, 65536, 65536, 196608, 256, 118272,
                                256, 256, 768, 768, 16777216};
    bool srt = true;
    for (int i = 0; i < 11; ++i)
      if (in_sizes[i] != ssz[i]) { srt = false; break; }
    if (srt) {
      idx[0] = 10; idx[1] = 5; idx[2] = 7; idx[3] = 6; idx[4] = 9; idx[5] = 8;
      idx[6] = 2;  idx[7] = 0; idx[8] = 3; idx[9] = 1; idx[10] = 4;
    }
  }
  const float* x   = (const float*)d_in[idx[0]];
  const float* ctx = (const float*)d_in[idx[1]];
  const float* gng = (const float*)d_in[idx[2]];
  const float* gnb = (const float*)d_in[idx[3]];
  const float* lng = (const float*)d_in[idx[4]];
  const float* lnb = (const float*)d_in[idx[5]];
  const float* Wq  = (const float*)d_in[idx[6]];
  const float* Wk  = (const float*)d_in[idx[7]];
  const float* Wv  = (const float*)d_in[idx[8]];
  const float* Wo  = (const float*)d_in[idx[9]];
  const float* bo  = (const float*)d_in[idx[10]];
  float* out = (float*)d_out;

  u16* ws = (u16*)d_ws;
  float* stats = (float*)ws;
  float* gsum = stats, *gsq = stats + 16;
  u16* wqt_hi = ws + 128;
  u16* wqt_lo = wqt_hi + 65536;
  u16* wot_hi = wqt_lo + 65536;
  u16* wot_lo = wot_hi + 65536;
  u16* kws_hi = wot_lo + 65536;
  u16* kws_lo = kws_hi + 49152;
  u16* vtw_hi = kws_lo + 49152;
  u16* vtw_lo = vtw_hi + 49152;

  prep_w<<<dim3(16, 16, 2), 256, 0, stream>>>(Wq, Wo, wqt_hi, wqt_lo, wot_hi, wot_lo,
                                              stats);
  gn_partial<<<512, 256, 0, stream>>>(x, gsum, gsq);
  ln_kv<<<dim3(96, 2), 256, 0, stream>>>(ctx, lng, lnb, Wk, Wv,
                                         kws_hi, kws_lo, vtw_hi, vtw_lo);
  fused_qao<<<2048, 256, 0, stream>>>(x, wqt_hi, wqt_lo, wot_hi, wot_lo,
                                      kws_hi, kws_lo, vtw_hi, vtw_lo,
                                      gng, gnb, gsum, gsq, bo, out);
}